// Round 15
// baseline (297.564 us; speedup 1.0000x reference)
//
#include <hip/hip_runtime.h>
#include <hip/hip_bf16.h>

#define N_NODES 50000
#define N_EDGES 800000
#define NF      64
#define NG      50
#define NPG     (N_NODES / NG)   // 1000 nodes per graph
#define SCAN_NBLK ((N_NODES + 255) / 256)   // 196
#define MCHUNK  20               // blocks per graph for means
#define MROWS   (NPG / MCHUNK)   // 50 nodes per means block
#define NTILES  (N_NODES / 16)   // 3125 exact
#define GATHER_BLKS ((NTILES + 3) / 4)      // 782: one tile per wave
#define INIT_BLKS ((N_NODES * 32 + 255) / 256)  // 6250
// R25 bucket-radix CSR build (replaces 800K-atomic deg+fill, R22 ceiling):
#define NBKT ((N_NODES + 255) / 256)   // 196 coarse buckets (col>>8)
#define BKT_CAP 6144                   // mean 4096, sigma ~62 -> +33 sigma
#define P1_EPB 4096                    // edges per pass-1 block
#define P1_BLKS ((N_EDGES + P1_EPB - 1) / P1_EPB)   // 196

typedef __attribute__((ext_vector_type(8))) short bf16x8;
typedef __attribute__((ext_vector_type(4))) float f32x4;
typedef unsigned short u16;
typedef unsigned char u8;

// round-half-up fp32->bf16 pair pack (inputs are finite)
__device__ inline unsigned pkbf(float a, float b) {
    unsigned ua = __float_as_uint(a) + 0x8000u;
    unsigned ub = __float_as_uint(b) + 0x8000u;
    return (ua >> 16) | (ub & 0xFFFF0000u);
}
__device__ inline short bf1(float a) {
    return (short)((__float_as_uint(a) + 0x8000u) >> 16);
}
__device__ inline float lo2f(unsigned u) { return __uint_as_float(u << 16); }
__device__ inline float hi2f(unsigned u) { return __uint_as_float(u & 0xFFFF0000u); }
// packed accumulate: float2 adds -> v_pk_add_f32
__device__ inline void accp(float2* a, uint4 v) {
    a[0].x += lo2f(v.x); a[0].y += hi2f(v.x);
    a[1].x += lo2f(v.y); a[1].y += hi2f(v.y);
    a[2].x += lo2f(v.z); a[2].y += hi2f(v.z);
    a[3].x += lo2f(v.w); a[3].y += hi2f(v.w);
}

// ---------------------------------------------------------------------------
// R25 pass 1: bucket edges by col>>8 into fixed-stride regions. Per-edge
// work uses LDS atomics only; ONE global atomic per (block, non-empty
// bucket) ~ 38K total. Init embeddings fused as extra blocks.
__global__ void k_bucket_init(const int* __restrict__ row, const int* __restrict__ col,
                              int* __restrict__ bktCnt, unsigned* __restrict__ bktData,
                              const float* __restrict__ x, const float* __restrict__ Wi,
                              const float* __restrict__ We1,
                              u16* __restrict__ cur, u16* __restrict__ h) {
    if (blockIdx.x < P1_BLKS) {
        __shared__ int lh[256], lbase[256];
        int t = threadIdx.x;
        lh[t] = 0;
        __syncthreads();
        int e0 = blockIdx.x * P1_EPB;
        int myb[16], myr[16];
        unsigned mypk[16];
#pragma unroll
        for (int i = 0; i < 16; i++) {
            int e = e0 + i * 256 + t;
            myb[i] = -1;
            if (e < N_EDGES) {
                int c = col[e];
                mypk[i] = ((unsigned)c << 16) | (unsigned)row[e];
                int b = c >> 8;
                myb[i] = b;
                myr[i] = atomicAdd(&lh[b], 1);   // LDS: rank within block+bucket
            }
        }
        __syncthreads();
        if (lh[t] > 0) lbase[t] = atomicAdd(&bktCnt[t], lh[t]);
        __syncthreads();
#pragma unroll
        for (int i = 0; i < 16; i++)
            if (myb[i] >= 0)
                bktData[(size_t)myb[i] * BKT_CAP + lbase[myb[i]] + myr[i]] = mypk[i];
        return;
    }
    int idx = (blockIdx.x - P1_BLKS) * 256 + threadIdx.x;   // N*32
    int node = idx >> 5, q = idx & 31;
    if (node >= N_NODES) return;
    int f0 = 2 * q, f1 = 2 * q + 1;
    float4 xv = ((const float4*)x)[node];
    float c0 = xv.x * Wi[f0] + xv.y * Wi[64 + f0] + xv.z * Wi[128 + f0] + xv.w * Wi[192 + f0];
    float c1 = xv.x * Wi[f1] + xv.y * Wi[64 + f1] + xv.z * Wi[128 + f1] + xv.w * Wi[192 + f1];
    ((unsigned*)cur)[node * 32 + q] = pkbf(fmaxf(c0, 0.f), fmaxf(c1, 0.f));
    float h0 = xv.x * We1[f0] + xv.y * We1[63 + f0] + xv.z * We1[126 + f0] + xv.w * We1[189 + f0];
    h0 = fmaxf(h0, 0.f);
    float h1 = 0.f;
    if (f1 < 63) {
        h1 = xv.x * We1[f1] + xv.y * We1[63 + f1] + xv.z * We1[126 + f1] + xv.w * We1[189 + f1];
        h1 = fmaxf(h1, 0.f);
    }
    ((unsigned*)h)[node * 32 + q] = pkbf(h0, h1);
}

// R25 pass 2: block b builds bucket b's CSR (cols [b*256, b*256+256)) by
// col&255, all in LDS, zero per-edge global atomics. R28: row-sorting
// REVERTED — A/B across R12(unsorted,262.1)/R13(sorted,+insertion,292.3)/
// R14(sorted,band-scatter,269.5) shows sorted lists never beat unsorted:
// the gather is in-flight-limited, not source-locality-limited (consistent
// with R23/R9 nulls). Keeps: folded dmax + degree-histogram (saves a
// launch), LDS staging + coalesced csr writeout.
__global__ __launch_bounds__(256) void k_bsort(
        const unsigned* __restrict__ bktData, const int* __restrict__ bktCnt,
        int* __restrict__ deg, int* __restrict__ rowptr, u16* __restrict__ csr,
        int* __restrict__ dmax, int* __restrict__ hist) {
    int b = blockIdx.x, t = threadIdx.x;
    int cnt = bktCnt[b];
    int p = (t < b) ? bktCnt[t] : 0;     // b <= 195 < 256
    for (int off = 32; off; off >>= 1) p += __shfl_xor(p, off, 64);
    __shared__ int sr[4];
    if ((t & 63) == 0) sr[t >> 6] = p;
    __shared__ int lh[256], hh[256];
    lh[t] = 0; hh[t] = 0;
    __syncthreads();
    int prev = sr[0] + sr[1] + sr[2] + sr[3];
    const unsigned* bd = bktData + (size_t)b * BKT_CAP;
    for (int i = t; i < cnt; i += 256)
        atomicAdd(&lh[(bd[i] >> 16) & 255], 1);
    __syncthreads();
    int myh = lh[t];
    int node = b * 256 + t;
    // dmax + degree histogram (folded k_blocksum)
    int mm = myh;
    for (int off = 32; off; off >>= 1) mm = max(mm, __shfl_xor(mm, off, 64));
    if ((t & 63) == 0) atomicMax(dmax, mm);
    if (node < N_NODES) atomicAdd(&hh[min(myh, 255)], 1);
    __shared__ int s[256];
    s[t] = myh;
    __syncthreads();
    for (int off = 1; off < 256; off <<= 1) {
        int u = (t >= off) ? s[t - off] : 0;
        __syncthreads();
        s[t] += u;
        __syncthreads();
    }
    __shared__ int lof[256];
    lof[t] = s[t] - myh;                 // exclusive offset within bucket
    if (node < N_NODES) { deg[node] = myh; rowptr[node] = prev + lof[t]; }
    if (b == 0 && t == 0) rowptr[N_NODES] = N_EDGES;
    if (hh[t]) atomicAdd(&hist[t], hh[t]);
    __shared__ int curs[256];
    curs[t] = 0;
    __shared__ u16 csr_l[BKT_CAP];       // 12.3KB
    __syncthreads();
    for (int i = t; i < cnt; i += 256) {
        unsigned pk = bd[i];
        int ln = (pk >> 16) & 255;
        int pos = atomicAdd(&curs[ln], 1);  // LDS
        csr_l[lof[ln] + pos] = (u16)(pk & 0xFFFFu);
    }
    __syncthreads();
    for (int i = t; i < cnt; i += 256) csr[prev + i] = csr_l[i];
}

// Two-level counting-sort perm (R18 pattern), DESCENDING degree (R24: the
// straggler tail of each gather kernel is the shortest lists).
__global__ __launch_bounds__(256) void k_permsort(
        const int* __restrict__ deg, const int* __restrict__ hist,
        int* __restrict__ binBump, int* __restrict__ perm) {
    int b = blockIdx.x, t = threadIdx.x;
    __shared__ int lh[256], lbase[256];
    lh[t] = 0;
    __syncthreads();
    int i = b * 256 + t;
    int v = (i < N_NODES) ? deg[i] : 0;
    int bin = min(v, 255);
    int rank = 0;
    if (i < N_NODES) rank = atomicAdd(&lh[bin], 1);   // LDS: local rank
    __shared__ int s[256];
    int hv = hist[t];
    s[t] = hv;
    __syncthreads();
    for (int off = 1; off < 256; off <<= 1) {
        int u = (t >= off) ? s[t - off] : 0;
        __syncthreads();
        s[t] += u;
        __syncthreads();
    }
    int total = s[255];
    int hpref = total - s[t];   // base for bin t in DESCENDING-degree order
    if (lh[t] > 0) lbase[t] = hpref + atomicAdd(&binBump[t], lh[t]);
    __syncthreads();
    if (i < N_NODES) perm[lbase[bin] + rank] = i;
}

// Per-wave fused gather. R28: 8-edge pipeline, SINGLE accumulator bank —
// 16 uint4 (64 VGPR) in flight + 16 acc + ~30 misc ~= 115 VGPR <= 128, so
// 3 waves/SIMD (grid-limited) hold and per-SIMD in-flight goes 36 -> 48.
// R15's depth-8 failure was the SECOND acc bank (+16 VGPR) crossing the
// 128 boundary -> spill. Tripwire: flayer VGPR >= 130 or WRITE_SIZE
// ballooning means spill -> revert to depth 6.
__device__ inline void gather_tile(const u16* __restrict__ src,
                                   const int* __restrict__ rowptr,
                                   const u16* __restrict__ csr,
                                   int node, int m, int q, int wv,
                                   short (*AT)[16][64]) {
    int beg = rowptr[node], end = rowptr[node + 1];
    float2 ac[8];
#pragma unroll
    for (int i = 0; i < 8; i++) ac[i] = make_float2(0.f, 0.f);
    int j = beg;
    for (; j + 7 < end; j += 8) {
        int r0 = csr[j],     r1 = csr[j + 1], r2 = csr[j + 2], r3 = csr[j + 3];
        int r4 = csr[j + 4], r5 = csr[j + 5], r6 = csr[j + 6], r7 = csr[j + 7];
        const uint4* p0 = (const uint4*)(src + (size_t)r0 * 64 + q * 16);
        const uint4* p1 = (const uint4*)(src + (size_t)r1 * 64 + q * 16);
        const uint4* p2 = (const uint4*)(src + (size_t)r2 * 64 + q * 16);
        const uint4* p3 = (const uint4*)(src + (size_t)r3 * 64 + q * 16);
        const uint4* p4 = (const uint4*)(src + (size_t)r4 * 64 + q * 16);
        const uint4* p5 = (const uint4*)(src + (size_t)r5 * 64 + q * 16);
        const uint4* p6 = (const uint4*)(src + (size_t)r6 * 64 + q * 16);
        const uint4* p7 = (const uint4*)(src + (size_t)r7 * 64 + q * 16);
        uint4 v00 = p0[0], v01 = p0[1];
        uint4 v10 = p1[0], v11 = p1[1];
        uint4 v20 = p2[0], v21 = p2[1];
        uint4 v30 = p3[0], v31 = p3[1];
        uint4 v40 = p4[0], v41 = p4[1];
        uint4 v50 = p5[0], v51 = p5[1];
        uint4 v60 = p6[0], v61 = p6[1];
        uint4 v70 = p7[0], v71 = p7[1];
        accp(ac, v00); accp(ac + 4, v01);
        accp(ac, v10); accp(ac + 4, v11);
        accp(ac, v20); accp(ac + 4, v21);
        accp(ac, v30); accp(ac + 4, v31);
        accp(ac, v40); accp(ac + 4, v41);
        accp(ac, v50); accp(ac + 4, v51);
        accp(ac, v60); accp(ac + 4, v61);
        accp(ac, v70); accp(ac + 4, v71);
    }
    for (; j + 3 < end; j += 4) {
        int r0 = csr[j], r1 = csr[j + 1], r2 = csr[j + 2], r3 = csr[j + 3];
        const uint4* p0 = (const uint4*)(src + (size_t)r0 * 64 + q * 16);
        const uint4* p1 = (const uint4*)(src + (size_t)r1 * 64 + q * 16);
        const uint4* p2 = (const uint4*)(src + (size_t)r2 * 64 + q * 16);
        const uint4* p3 = (const uint4*)(src + (size_t)r3 * 64 + q * 16);
        uint4 v00 = p0[0], v01 = p0[1];
        uint4 v10 = p1[0], v11 = p1[1];
        uint4 v20 = p2[0], v21 = p2[1];
        uint4 v30 = p3[0], v31 = p3[1];
        accp(ac, v00); accp(ac + 4, v01);
        accp(ac, v10); accp(ac + 4, v11);
        accp(ac, v20); accp(ac + 4, v21);
        accp(ac, v30); accp(ac + 4, v31);
    }
    for (; j < end; j++) {
        int r = csr[j];
        const uint4* p = (const uint4*)(src + (size_t)r * 64 + q * 16);
        uint4 v0 = p[0], v1 = p[1];
        accp(ac, v0); accp(ac + 4, v1);
    }
    float inv = 1.0f / (float)(end - beg);   // deg > 0 always
    uint4 lo, hi;
    lo.x = pkbf(ac[0].x * inv, ac[0].y * inv);
    lo.y = pkbf(ac[1].x * inv, ac[1].y * inv);
    lo.z = pkbf(ac[2].x * inv, ac[2].y * inv);
    lo.w = pkbf(ac[3].x * inv, ac[3].y * inv);
    hi.x = pkbf(ac[4].x * inv, ac[4].y * inv);
    hi.y = pkbf(ac[5].x * inv, ac[5].y * inv);
    hi.z = pkbf(ac[6].x * inv, ac[6].y * inv);
    hi.w = pkbf(ac[7].x * inv, ac[7].y * inv);
    *(uint4*)&AT[wv][m][((2 * q) ^ (m & 7)) * 8]     = lo;
    *(uint4*)&AT[wv][m][((2 * q + 1) ^ (m & 7)) * 8] = hi;
}

// fused h-gather + edge_emb MFMA, degree-sorted tiles via perm.
__global__ __launch_bounds__(256) void k_edge_f(
        const u16* __restrict__ h, const int* __restrict__ rowptr,
        const u16* __restrict__ csr, const int* __restrict__ dmax,
        const float* __restrict__ We2, const int* __restrict__ perm,
        u16* __restrict__ ee) {
    __shared__ unsigned SB[2][4][64][4];   // 8KB
    __shared__ short AT[4][16][64];        // 8KB
    int t = threadIdx.x;
    for (int F = t; F < 512; F += 256) {
        int ks = F >> 8, tile = (F >> 6) & 3, ln = F & 63;
        int c = ln & 15, qq = ln >> 4;
        const float* W = We2 + (ks * 32 + qq * 8) * 64 + tile * 16 + c;
        unsigned d0 = pkbf(W[0],       W[64]);
        unsigned d1 = pkbf(W[2 * 64],  W[3 * 64]);
        unsigned d2 = pkbf(W[4 * 64],  W[5 * 64]);
        unsigned d3 = pkbf(W[6 * 64],  W[7 * 64]);
        int slot = ln ^ ((ln >> 3) & 7);
        SB[ks][tile][slot][0] = d0; SB[ks][tile][slot][1] = d1;
        SB[ks][tile][slot][2] = d2; SB[ks][tile][slot][3] = d3;
    }
    __syncthreads();
    int wv = t >> 6, lane = t & 63;
    int m = lane & 15, quad = lane >> 4;
    int slot = lane ^ ((lane >> 3) & 7);
    float idm = 1.0f / (float)dmax[0];
    for (int tb = blockIdx.x * 4 + wv; tb < NTILES; tb += gridDim.x * 4) {
        int base = tb * 16;
        int pn = perm[base + m];
        gather_tile(h, rowptr, csr, pn, m, quad, wv, AT);
        float dv = (float)(rowptr[pn + 1] - rowptr[pn]) * idm;
        int prw[4];
#pragma unroll
        for (int r = 0; r < 4; r++) prw[r] = perm[base + quad * 4 + r];
        f32x4 acc[4];
#pragma unroll
        for (int i = 0; i < 4; i++) acc[i] = (f32x4){0.f, 0.f, 0.f, 0.f};
#pragma unroll
        for (int ks = 0; ks < 2; ks++) {
            int gp = (ks * 4 + quad) ^ (m & 7);
            bf16x8 a = *(const bf16x8*)&AT[wv][m][gp * 8];
            if (ks == 1 && quad == 3) a[7] = bf1(dv);   // k=63 column
#pragma unroll
            for (int tile = 0; tile < 4; tile++) {
                bf16x8 b = *(const bf16x8*)&SB[ks][tile][slot][0];
                acc[tile] = __builtin_amdgcn_mfma_f32_16x16x32_bf16(a, b, acc[tile], 0, 0, 0);
            }
        }
#pragma unroll
        for (int tile = 0; tile < 4; tile++)
#pragma unroll
            for (int r = 0; r < 4; r++)
                ee[(size_t)prw[r] * 64 + tile * 16 + m] =
                    (u16)bf1(fmaxf(acc[tile][r], 0.f));
    }
}

// fused gather + MPNN layer, degree-sorted tiles via perm. XT: agg tile for
// GEMM1 then msg tile for GEMM2 (disjoint lifetimes, 40KB LDS total).
template <bool F32OUT>
__global__ __launch_bounds__(256) void k_flayer(
        const u16* __restrict__ cur, const u16* __restrict__ ee,
        const int* __restrict__ rowptr, const u16* __restrict__ csr,
        const float* __restrict__ Wm, const float* __restrict__ Wu,
        const int* __restrict__ perm, void* __restrict__ outp) {
    __shared__ unsigned SB[2][4][4][64][4];   // 32KB
    __shared__ short XT[4][16][64];           // 8KB
    int t = threadIdx.x;
    for (int F = t; F < 2048; F += 256) {
        int g = F >> 10, ks = (F >> 8) & 3, tile = (F >> 6) & 3, ln = F & 63;
        int c = ln & 15, qq = ln >> 4;
        const float* W = (g ? Wu : Wm) + (ks * 32 + qq * 8) * 64 + tile * 16 + c;
        unsigned d0 = pkbf(W[0],      W[64]);
        unsigned d1 = pkbf(W[2 * 64], W[3 * 64]);
        unsigned d2 = pkbf(W[4 * 64], W[5 * 64]);
        unsigned d3 = pkbf(W[6 * 64], W[7 * 64]);
        int slot = ln ^ ((ln >> 3) & 7);
        SB[g][ks][tile][slot][0] = d0; SB[g][ks][tile][slot][1] = d1;
        SB[g][ks][tile][slot][2] = d2; SB[g][ks][tile][slot][3] = d3;
    }
    __syncthreads();
    int wv = t >> 6, lane = t & 63;
    int m = lane & 15, quad = lane >> 4;
    int slot = lane ^ ((lane >> 3) & 7);
    for (int tb = blockIdx.x * 4 + wv; tb < NTILES; tb += gridDim.x * 4) {
        int base = tb * 16;
        int pn = perm[base + m];
        gather_tile(cur, rowptr, csr, pn, m, quad, wv, XT);
        const u16* erow = ee  + (size_t)pn * 64;
        const u16* crow = cur + (size_t)pn * 64;
        int prw[4];
#pragma unroll
        for (int r = 0; r < 4; r++) prw[r] = perm[base + quad * 4 + r];
        f32x4 acc[4];
#pragma unroll
        for (int i = 0; i < 4; i++) acc[i] = (f32x4){0.f, 0.f, 0.f, 0.f};
        // GEMM1: k 0..63 = agg (XT), 64..127 = ee (global)
#pragma unroll
        for (int ks = 0; ks < 4; ks++) {
            bf16x8 a;
            if (ks < 2) {
                int gp = (ks * 4 + quad) ^ (m & 7);
                a = *(const bf16x8*)&XT[wv][m][gp * 8];
            } else {
                a = *(const bf16x8*)(erow + (ks - 2) * 32 + quad * 8);
            }
#pragma unroll
            for (int tile = 0; tile < 4; tile++) {
                bf16x8 b = *(const bf16x8*)&SB[0][ks][tile][slot][0];
                acc[tile] = __builtin_amdgcn_mfma_f32_16x16x32_bf16(a, b, acc[tile], 0, 0, 0);
            }
        }
        // relu(msg) -> XT (reuse) in A-readable swizzled layout (wave-private)
#pragma unroll
        for (int tile = 0; tile < 4; tile++)
#pragma unroll
            for (int r = 0; r < 4; r++) {
                int node = quad * 4 + r;
                int f = tile * 16 + m;
                int sidx = (((f >> 3) ^ (node & 7)) << 3) | (f & 7);
                XT[wv][node][sidx] = bf1(fmaxf(acc[tile][r], 0.f));
            }
        // GEMM2: k 0..63 = cur (global bf16), 64..127 = msg (XT)
#pragma unroll
        for (int i = 0; i < 4; i++) acc[i] = (f32x4){0.f, 0.f, 0.f, 0.f};
#pragma unroll
        for (int ks = 0; ks < 4; ks++) {
            bf16x8 a;
            if (ks < 2) {
                a = *(const bf16x8*)(crow + ks * 32 + quad * 8);
            } else {
                int gp = ((ks - 2) * 4 + quad) ^ (m & 7);
                a = *(const bf16x8*)&XT[wv][m][gp << 3];
            }
#pragma unroll
            for (int tile = 0; tile < 4; tile++) {
                bf16x8 b = *(const bf16x8*)&SB[1][ks][tile][slot][0];
                acc[tile] = __builtin_amdgcn_mfma_f32_16x16x32_bf16(a, b, acc[tile], 0, 0, 0);
            }
        }
#pragma unroll
        for (int tile = 0; tile < 4; tile++)
#pragma unroll
            for (int r = 0; r < 4; r++) {
                float v = fmaxf(acc[tile][r], 0.f);
                size_t oi = (size_t)prw[r] * 64 + tile * 16 + m;
                if (F32OUT) ((float*)outp)[oi] = v;
                else        ((u16*)outp)[oi] = (u16)bf1(v);
            }
    }
}

// R21: atomic-free means partials (distinct addresses, no done-counter).
__global__ __launch_bounds__(256) void k_means2(const float* __restrict__ cur,
                                                float* __restrict__ pmeans) {
    int g = blockIdx.x / MCHUNK;
    int c = blockIdx.x % MCHUNK;
    int t = threadIdx.x, f = t & 63, q = t >> 6;
    int base = g * NPG + c * MROWS;
    float acc = 0.f;
    for (int n = base + q; n < base + MROWS; n += 4) acc += cur[(size_t)n * 64 + f];
    __shared__ float red[4][64];
    red[q][f] = acc;
    __syncthreads();
    if (q == 0)
        pmeans[(size_t)(g * MCHUNK + c) * 64 + f] =
            red[0][f] + red[1][f] + red[2][f] + red[3][f];
}

// r1[g] = sum_f relu((mean[g] @ Wp)[f]) * Wr[f]. One block.
__global__ __launch_bounds__(256) void k_pool2(
        const float* __restrict__ pmeans, const float* __restrict__ Wp,
        const float* __restrict__ Wr, float* __restrict__ r1) {
    __shared__ float sm[4][64];
    int wv = threadIdx.x >> 6, lane = threadIdx.x & 63;
    for (int g = wv; g < NG; g += 4) {
        float m = 0.f;
        const float* pm = pmeans + (size_t)g * MCHUNK * 64 + lane;
#pragma unroll
        for (int c = 0; c < MCHUNK; c++) m += pm[c * 64];
        sm[wv][lane] = m * (1.0f / NPG);
        float a2 = 0.f;
#pragma unroll 16
        for (int k = 0; k < 64; k++) a2 = fmaf(sm[wv][k], Wp[k * 64 + lane], a2);
        float v = fmaxf(a2, 0.f) * Wr[lane];
        for (int off = 32; off; off >>= 1) v += __shfl_xor(v, off, 64);
        if (lane == 0) r1[g] = v;
    }
}

// out[n] = b + r1[batch[n]] + dot(relu(cur[n]), Wr[64:])
__global__ void k_read2(const float* __restrict__ cur, const float* __restrict__ r1,
                        const int* __restrict__ batch, const float* __restrict__ Wr,
                        const float* __restrict__ br, float* __restrict__ out) {
    int idx = blockIdx.x * 256 + threadIdx.x;
    int node = idx >> 4;
    if (node >= N_NODES) return;
    int q = idx & 15;
    float4 c = *(const float4*)(cur + (size_t)node * 64 + q * 4);
    float4 w = *(const float4*)(Wr + 64 + q * 4);
    float v = fmaxf(c.x, 0.f) * w.x + fmaxf(c.y, 0.f) * w.y
            + fmaxf(c.z, 0.f) * w.z + fmaxf(c.w, 0.f) * w.w;
    v += __shfl_xor(v, 1, 64); v += __shfl_xor(v, 2, 64);
    v += __shfl_xor(v, 4, 64); v += __shfl_xor(v, 8, 64);
    if (q == 0) out[node] = v + r1[batch[node]] + br[0];
}

// ---------------------------------------------------------------------------
extern "C" void kernel_launch(void* const* d_in, const int* in_sizes, int n_in,
                              void* d_out, int out_size, void* d_ws, size_t ws_size,
                              hipStream_t stream) {
    const float* x    = (const float*)d_in[0];
    const float* Wi   = (const float*)d_in[1];
    const float* We1  = (const float*)d_in[2];
    const float* We2  = (const float*)d_in[3];
    const float* Wm   = (const float*)d_in[4];   // [3,128,64]
    const float* Wu   = (const float*)d_in[5];   // [3,128,64]
    const float* Wp   = (const float*)d_in[6];
    const float* Wr   = (const float*)d_in[7];
    const float* br   = (const float*)d_in[8];
    const int*   ei   = (const int*)d_in[9];     // [2,E]
    const int*   batch= (const int*)d_in[10];
    const int* row = ei;
    const int* col = ei + N_EDGES;
    float* out = (float*)d_out;

    char* w = (char*)d_ws;
    size_t off = 0;
    auto carve = [&](size_t bytes) -> void* {
        void* p = (void*)(w + off);
        off += (bytes + 255) & ~(size_t)255;
        return p;
    };
    // zero-init region (one memset: dmax + hist + binBump + bktCnt)
    int*   dmax     = (int*)carve(256);
    int*   hist     = (int*)carve(256 * 4);
    int*   binBump  = (int*)carve(256 * 4);
    int*   bktCnt   = (int*)carve(256 * 4);
    size_t zero_span = off;
    unsigned* bktData = (unsigned*)carve((size_t)NBKT * BKT_CAP * 4);  // 4.8MB
    int*   deg      = (int*)carve((size_t)N_NODES * 4);   // dense, fully written
    int*   rowptr   = (int*)carve((size_t)(N_NODES + 1) * 4);
    u16*   csr      = (u16*)carve((size_t)N_EDGES * 2);
    int*   perm     = (int*)carve((size_t)N_NODES * 4);
    float* pmeans   = (float*)carve((size_t)NG * MCHUNK * 64 * 4);
    u16*   bufA     = (u16*)carve((size_t)N_NODES * 64 * 2);
    u16*   bufB     = (u16*)carve((size_t)N_NODES * 64 * 2);
    u16*   ee       = (u16*)carve((size_t)N_NODES * 64 * 2);
    float* curF     = (float*)carve((size_t)N_NODES * 64 * 4);
    float* r1       = (float*)carve((size_t)NG * 4);

    hipMemsetAsync(d_ws, 0, zero_span, stream);

    // R25 bucket-radix CSR build (atomic-light) fused with node init
    k_bucket_init<<<P1_BLKS + INIT_BLKS, 256, 0, stream>>>(row, col, bktCnt, bktData,
                                                           x, Wi, We1, bufA, bufB);
    // bsort: CSR + deg + rowptr + dmax + hist (unsorted lists, R28)
    k_bsort   <<<NBKT, 256, 0, stream>>>(bktData, bktCnt, deg, rowptr, csr,
                                         dmax, hist);
    // descending-degree counting-sort perm
    k_permsort<<<SCAN_NBLK, 256, 0, stream>>>(deg, hist, binBump, perm);

    // fused h-gather + edge embedding (bufB = h)
    k_edge_f<<<GATHER_BLKS, 256, 0, stream>>>(bufB, rowptr, csr, dmax, We2, perm, ee);

    // fused gather+layer x3: A->B, B->A, A->curF(fp32)
    k_flayer<false><<<GATHER_BLKS, 256, 0, stream>>>(bufA, ee, rowptr, csr,
                                                     Wm, Wu, perm, bufB);
    k_flayer<false><<<GATHER_BLKS, 256, 0, stream>>>(bufB, ee, rowptr, csr,
                                                     Wm + 128 * 64, Wu + 128 * 64,
                                                     perm, bufA);
    k_flayer<true> <<<GATHER_BLKS, 256, 0, stream>>>(bufA, ee, rowptr, csr,
                                                     Wm + 2 * 128 * 64, Wu + 2 * 128 * 64,
                                                     perm, curF);

    // atomic-free means partials -> tiny pool kernel
    k_means2<<<NG * MCHUNK, 256, 0, stream>>>(curF, pmeans);
    k_pool2 <<<1, 256, 0, stream>>>(pmeans, Wp, Wr, r1);
    k_read2<<<(N_NODES * 16 + 255) / 256, 256, 0, stream>>>(curF, r1, batch, Wr, br, out);
}

// Round 16
// 257.435 us; speedup vs baseline: 1.1559x; 1.1559x over previous
//
#include <hip/hip_runtime.h>
#include <hip/hip_bf16.h>

#define N_NODES 50000
#define N_EDGES 800000
#define NF      64
#define NG      50
#define NPG     (N_NODES / NG)   // 1000 nodes per graph
#define SCAN_NBLK ((N_NODES + 255) / 256)   // 196
#define MCHUNK  20               // blocks per graph for means
#define MROWS   (NPG / MCHUNK)   // 50 nodes per means block
#define NTILES  (N_NODES / 16)   // 3125 exact
#define GATHER_BLKS ((NTILES + 3) / 4)      // 782: one tile per wave
#define INIT_BLKS ((N_NODES * 32 + 255) / 256)  // 6250
// R25 bucket-radix CSR build (replaces 800K-atomic deg+fill, R22 ceiling):
#define NBKT ((N_NODES + 255) / 256)   // 196 coarse buckets (col>>8)
#define BKT_CAP 6144                   // mean 4096, sigma ~62 -> +33 sigma
#define P1_EPB 4096                    // edges per pass-1 block
#define P1_BLKS ((N_EDGES + P1_EPB - 1) / P1_EPB)   // 196

typedef __attribute__((ext_vector_type(8))) short bf16x8;
typedef __attribute__((ext_vector_type(4))) float f32x4;
typedef unsigned short u16;
typedef unsigned char u8;

// round-half-up fp32->bf16 pair pack (inputs are finite)
__device__ inline unsigned pkbf(float a, float b) {
    unsigned ua = __float_as_uint(a) + 0x8000u;
    unsigned ub = __float_as_uint(b) + 0x8000u;
    return (ua >> 16) | (ub & 0xFFFF0000u);
}
__device__ inline short bf1(float a) {
    return (short)((__float_as_uint(a) + 0x8000u) >> 16);
}
__device__ inline float lo2f(unsigned u) { return __uint_as_float(u << 16); }
__device__ inline float hi2f(unsigned u) { return __uint_as_float(u & 0xFFFF0000u); }
// packed accumulate: float2 adds -> v_pk_add_f32
__device__ inline void accp(float2* a, uint4 v) {
    a[0].x += lo2f(v.x); a[0].y += hi2f(v.x);
    a[1].x += lo2f(v.y); a[1].y += hi2f(v.y);
    a[2].x += lo2f(v.z); a[2].y += hi2f(v.z);
    a[3].x += lo2f(v.w); a[3].y += hi2f(v.w);
}

// ---------------------------------------------------------------------------
// R25 pass 1: bucket edges by col>>8 into fixed-stride regions. Per-edge
// work uses LDS atomics only; ONE global atomic per (block, non-empty
// bucket) ~ 38K total. Init embeddings fused as extra blocks.
__global__ void k_bucket_init(const int* __restrict__ row, const int* __restrict__ col,
                              int* __restrict__ bktCnt, unsigned* __restrict__ bktData,
                              const float* __restrict__ x, const float* __restrict__ Wi,
                              const float* __restrict__ We1,
                              u16* __restrict__ cur, u16* __restrict__ h) {
    if (blockIdx.x < P1_BLKS) {
        __shared__ int lh[256], lbase[256];
        int t = threadIdx.x;
        lh[t] = 0;
        __syncthreads();
        int e0 = blockIdx.x * P1_EPB;
        int myb[16], myr[16];
        unsigned mypk[16];
#pragma unroll
        for (int i = 0; i < 16; i++) {
            int e = e0 + i * 256 + t;
            myb[i] = -1;
            if (e < N_EDGES) {
                int c = col[e];
                mypk[i] = ((unsigned)c << 16) | (unsigned)row[e];
                int b = c >> 8;
                myb[i] = b;
                myr[i] = atomicAdd(&lh[b], 1);   // LDS: rank within block+bucket
            }
        }
        __syncthreads();
        if (lh[t] > 0) lbase[t] = atomicAdd(&bktCnt[t], lh[t]);
        __syncthreads();
#pragma unroll
        for (int i = 0; i < 16; i++)
            if (myb[i] >= 0)
                bktData[(size_t)myb[i] * BKT_CAP + lbase[myb[i]] + myr[i]] = mypk[i];
        return;
    }
    int idx = (blockIdx.x - P1_BLKS) * 256 + threadIdx.x;   // N*32
    int node = idx >> 5, q = idx & 31;
    if (node >= N_NODES) return;
    int f0 = 2 * q, f1 = 2 * q + 1;
    float4 xv = ((const float4*)x)[node];
    float c0 = xv.x * Wi[f0] + xv.y * Wi[64 + f0] + xv.z * Wi[128 + f0] + xv.w * Wi[192 + f0];
    float c1 = xv.x * Wi[f1] + xv.y * Wi[64 + f1] + xv.z * Wi[128 + f1] + xv.w * Wi[192 + f1];
    ((unsigned*)cur)[node * 32 + q] = pkbf(fmaxf(c0, 0.f), fmaxf(c1, 0.f));
    float h0 = xv.x * We1[f0] + xv.y * We1[63 + f0] + xv.z * We1[126 + f0] + xv.w * We1[189 + f0];
    h0 = fmaxf(h0, 0.f);
    float h1 = 0.f;
    if (f1 < 63) {
        h1 = xv.x * We1[f1] + xv.y * We1[63 + f1] + xv.z * We1[126 + f1] + xv.w * We1[189 + f1];
        h1 = fmaxf(h1, 0.f);
    }
    ((unsigned*)h)[node * 32 + q] = pkbf(h0, h1);
}

// R25 pass 2: block b builds bucket b's CSR (cols [b*256, b*256+256)) by
// col&255, all in LDS, zero per-edge global atomics. R28: row-sorting
// REVERTED (R12/R13/R14 A/B: sorted lists never beat unsorted — gather is
// in-flight-limited, not source-locality-limited). Keeps folded dmax +
// degree-histogram, LDS staging + coalesced csr writeout.
__global__ __launch_bounds__(256) void k_bsort(
        const unsigned* __restrict__ bktData, const int* __restrict__ bktCnt,
        int* __restrict__ deg, int* __restrict__ rowptr, u16* __restrict__ csr,
        int* __restrict__ dmax, int* __restrict__ hist) {
    int b = blockIdx.x, t = threadIdx.x;
    int cnt = bktCnt[b];
    int p = (t < b) ? bktCnt[t] : 0;     // b <= 195 < 256
    for (int off = 32; off; off >>= 1) p += __shfl_xor(p, off, 64);
    __shared__ int sr[4];
    if ((t & 63) == 0) sr[t >> 6] = p;
    __shared__ int lh[256], hh[256];
    lh[t] = 0; hh[t] = 0;
    __syncthreads();
    int prev = sr[0] + sr[1] + sr[2] + sr[3];
    const unsigned* bd = bktData + (size_t)b * BKT_CAP;
    for (int i = t; i < cnt; i += 256)
        atomicAdd(&lh[(bd[i] >> 16) & 255], 1);
    __syncthreads();
    int myh = lh[t];
    int node = b * 256 + t;
    // dmax + degree histogram (folded k_blocksum)
    int mm = myh;
    for (int off = 32; off; off >>= 1) mm = max(mm, __shfl_xor(mm, off, 64));
    if ((t & 63) == 0) atomicMax(dmax, mm);
    if (node < N_NODES) atomicAdd(&hh[min(myh, 255)], 1);
    __shared__ int s[256];
    s[t] = myh;
    __syncthreads();
    for (int off = 1; off < 256; off <<= 1) {
        int u = (t >= off) ? s[t - off] : 0;
        __syncthreads();
        s[t] += u;
        __syncthreads();
    }
    __shared__ int lof[256];
    lof[t] = s[t] - myh;                 // exclusive offset within bucket
    if (node < N_NODES) { deg[node] = myh; rowptr[node] = prev + lof[t]; }
    if (b == 0 && t == 0) rowptr[N_NODES] = N_EDGES;
    if (hh[t]) atomicAdd(&hist[t], hh[t]);
    __shared__ int curs[256];
    curs[t] = 0;
    __shared__ u16 csr_l[BKT_CAP];       // 12.3KB
    __syncthreads();
    for (int i = t; i < cnt; i += 256) {
        unsigned pk = bd[i];
        int ln = (pk >> 16) & 255;
        int pos = atomicAdd(&curs[ln], 1);  // LDS
        csr_l[lof[ln] + pos] = (u16)(pk & 0xFFFFu);
    }
    __syncthreads();
    for (int i = t; i < cnt; i += 256) csr[prev + i] = csr_l[i];
}

// Two-level counting-sort perm (R18 pattern), DESCENDING degree (R24: the
// straggler tail of each gather kernel is the shortest lists).
__global__ __launch_bounds__(256) void k_permsort(
        const int* __restrict__ deg, const int* __restrict__ hist,
        int* __restrict__ binBump, int* __restrict__ perm) {
    int b = blockIdx.x, t = threadIdx.x;
    __shared__ int lh[256], lbase[256];
    lh[t] = 0;
    __syncthreads();
    int i = b * 256 + t;
    int v = (i < N_NODES) ? deg[i] : 0;
    int bin = min(v, 255);
    int rank = 0;
    if (i < N_NODES) rank = atomicAdd(&lh[bin], 1);   // LDS: local rank
    __shared__ int s[256];
    int hv = hist[t];
    s[t] = hv;
    __syncthreads();
    for (int off = 1; off < 256; off <<= 1) {
        int u = (t >= off) ? s[t - off] : 0;
        __syncthreads();
        s[t] += u;
        __syncthreads();
    }
    int total = s[255];
    int hpref = total - s[t];   // base for bin t in DESCENDING-degree order
    if (lh[t] > 0) lbase[t] = hpref + atomicAdd(&binBump[t], lh[t]);
    __syncthreads();
    if (i < N_NODES) perm[lbase[bin] + rank] = i;
}

// Per-wave fused gather. SETTLED (R15-depth4 / R24-depth6 / R28-depth8 x2):
// the 6-edge pipeline (12 uint4 in flight, single acc bank, ~110 VGPR) is
// the measured optimum. Depth 8 fails BOTH ways: 2-bank spills (R15-era,
// WRITE 84MB); 1-bank hits VGPR=132 > 128 -> blocks/CU 4->3 AND near-ceiling
// scheduling serializes the batch (R15-run: occupancy 8%, +28us total).
// DO NOT revisit pipeline depth. Do not cap launch_bounds (R17).
__device__ inline void gather_tile(const u16* __restrict__ src,
                                   const int* __restrict__ rowptr,
                                   const u16* __restrict__ csr,
                                   int node, int m, int q, int wv,
                                   short (*AT)[16][64]) {
    int beg = rowptr[node], end = rowptr[node + 1];
    float2 ac[8];
#pragma unroll
    for (int i = 0; i < 8; i++) ac[i] = make_float2(0.f, 0.f);
    int j = beg;
    for (; j + 5 < end; j += 6) {
        int r0 = csr[j],     r1 = csr[j + 1], r2 = csr[j + 2];
        int r3 = csr[j + 3], r4 = csr[j + 4], r5 = csr[j + 5];
        const uint4* p0 = (const uint4*)(src + (size_t)r0 * 64 + q * 16);
        const uint4* p1 = (const uint4*)(src + (size_t)r1 * 64 + q * 16);
        const uint4* p2 = (const uint4*)(src + (size_t)r2 * 64 + q * 16);
        const uint4* p3 = (const uint4*)(src + (size_t)r3 * 64 + q * 16);
        const uint4* p4 = (const uint4*)(src + (size_t)r4 * 64 + q * 16);
        const uint4* p5 = (const uint4*)(src + (size_t)r5 * 64 + q * 16);
        uint4 v00 = p0[0], v01 = p0[1];
        uint4 v10 = p1[0], v11 = p1[1];
        uint4 v20 = p2[0], v21 = p2[1];
        uint4 v30 = p3[0], v31 = p3[1];
        uint4 v40 = p4[0], v41 = p4[1];
        uint4 v50 = p5[0], v51 = p5[1];
        accp(ac, v00); accp(ac + 4, v01);
        accp(ac, v10); accp(ac + 4, v11);
        accp(ac, v20); accp(ac + 4, v21);
        accp(ac, v30); accp(ac + 4, v31);
        accp(ac, v40); accp(ac + 4, v41);
        accp(ac, v50); accp(ac + 4, v51);
    }
    for (; j + 3 < end; j += 4) {
        int r0 = csr[j], r1 = csr[j + 1], r2 = csr[j + 2], r3 = csr[j + 3];
        const uint4* p0 = (const uint4*)(src + (size_t)r0 * 64 + q * 16);
        const uint4* p1 = (const uint4*)(src + (size_t)r1 * 64 + q * 16);
        const uint4* p2 = (const uint4*)(src + (size_t)r2 * 64 + q * 16);
        const uint4* p3 = (const uint4*)(src + (size_t)r3 * 64 + q * 16);
        uint4 v00 = p0[0], v01 = p0[1];
        uint4 v10 = p1[0], v11 = p1[1];
        uint4 v20 = p2[0], v21 = p2[1];
        uint4 v30 = p3[0], v31 = p3[1];
        accp(ac, v00); accp(ac + 4, v01);
        accp(ac, v10); accp(ac + 4, v11);
        accp(ac, v20); accp(ac + 4, v21);
        accp(ac, v30); accp(ac + 4, v31);
    }
    for (; j < end; j++) {
        int r = csr[j];
        const uint4* p = (const uint4*)(src + (size_t)r * 64 + q * 16);
        uint4 v0 = p[0], v1 = p[1];
        accp(ac, v0); accp(ac + 4, v1);
    }
    float inv = 1.0f / (float)(end - beg);   // deg > 0 always
    uint4 lo, hi;
    lo.x = pkbf(ac[0].x * inv, ac[0].y * inv);
    lo.y = pkbf(ac[1].x * inv, ac[1].y * inv);
    lo.z = pkbf(ac[2].x * inv, ac[2].y * inv);
    lo.w = pkbf(ac[3].x * inv, ac[3].y * inv);
    hi.x = pkbf(ac[4].x * inv, ac[4].y * inv);
    hi.y = pkbf(ac[5].x * inv, ac[5].y * inv);
    hi.z = pkbf(ac[6].x * inv, ac[6].y * inv);
    hi.w = pkbf(ac[7].x * inv, ac[7].y * inv);
    *(uint4*)&AT[wv][m][((2 * q) ^ (m & 7)) * 8]     = lo;
    *(uint4*)&AT[wv][m][((2 * q + 1) ^ (m & 7)) * 8] = hi;
}

// fused h-gather + edge_emb MFMA, degree-sorted tiles via perm.
__global__ __launch_bounds__(256) void k_edge_f(
        const u16* __restrict__ h, const int* __restrict__ rowptr,
        const u16* __restrict__ csr, const int* __restrict__ dmax,
        const float* __restrict__ We2, const int* __restrict__ perm,
        u16* __restrict__ ee) {
    __shared__ unsigned SB[2][4][64][4];   // 8KB
    __shared__ short AT[4][16][64];        // 8KB
    int t = threadIdx.x;
    for (int F = t; F < 512; F += 256) {
        int ks = F >> 8, tile = (F >> 6) & 3, ln = F & 63;
        int c = ln & 15, qq = ln >> 4;
        const float* W = We2 + (ks * 32 + qq * 8) * 64 + tile * 16 + c;
        unsigned d0 = pkbf(W[0],       W[64]);
        unsigned d1 = pkbf(W[2 * 64],  W[3 * 64]);
        unsigned d2 = pkbf(W[4 * 64],  W[5 * 64]);
        unsigned d3 = pkbf(W[6 * 64],  W[7 * 64]);
        int slot = ln ^ ((ln >> 3) & 7);
        SB[ks][tile][slot][0] = d0; SB[ks][tile][slot][1] = d1;
        SB[ks][tile][slot][2] = d2; SB[ks][tile][slot][3] = d3;
    }
    __syncthreads();
    int wv = t >> 6, lane = t & 63;
    int m = lane & 15, quad = lane >> 4;
    int slot = lane ^ ((lane >> 3) & 7);
    float idm = 1.0f / (float)dmax[0];
    for (int tb = blockIdx.x * 4 + wv; tb < NTILES; tb += gridDim.x * 4) {
        int base = tb * 16;
        int pn = perm[base + m];
        gather_tile(h, rowptr, csr, pn, m, quad, wv, AT);
        float dv = (float)(rowptr[pn + 1] - rowptr[pn]) * idm;
        int prw[4];
#pragma unroll
        for (int r = 0; r < 4; r++) prw[r] = perm[base + quad * 4 + r];
        f32x4 acc[4];
#pragma unroll
        for (int i = 0; i < 4; i++) acc[i] = (f32x4){0.f, 0.f, 0.f, 0.f};
#pragma unroll
        for (int ks = 0; ks < 2; ks++) {
            int gp = (ks * 4 + quad) ^ (m & 7);
            bf16x8 a = *(const bf16x8*)&AT[wv][m][gp * 8];
            if (ks == 1 && quad == 3) a[7] = bf1(dv);   // k=63 column
#pragma unroll
            for (int tile = 0; tile < 4; tile++) {
                bf16x8 b = *(const bf16x8*)&SB[ks][tile][slot][0];
                acc[tile] = __builtin_amdgcn_mfma_f32_16x16x32_bf16(a, b, acc[tile], 0, 0, 0);
            }
        }
#pragma unroll
        for (int tile = 0; tile < 4; tile++)
#pragma unroll
            for (int r = 0; r < 4; r++)
                ee[(size_t)prw[r] * 64 + tile * 16 + m] =
                    (u16)bf1(fmaxf(acc[tile][r], 0.f));
    }
}

// fused gather + MPNN layer, degree-sorted tiles via perm. XT: agg tile for
// GEMM1 then msg tile for GEMM2 (disjoint lifetimes, 40KB LDS total).
template <bool F32OUT>
__global__ __launch_bounds__(256) void k_flayer(
        const u16* __restrict__ cur, const u16* __restrict__ ee,
        const int* __restrict__ rowptr, const u16* __restrict__ csr,
        const float* __restrict__ Wm, const float* __restrict__ Wu,
        const int* __restrict__ perm, void* __restrict__ outp) {
    __shared__ unsigned SB[2][4][4][64][4];   // 32KB
    __shared__ short XT[4][16][64];           // 8KB
    int t = threadIdx.x;
    for (int F = t; F < 2048; F += 256) {
        int g = F >> 10, ks = (F >> 8) & 3, tile = (F >> 6) & 3, ln = F & 63;
        int c = ln & 15, qq = ln >> 4;
        const float* W = (g ? Wu : Wm) + (ks * 32 + qq * 8) * 64 + tile * 16 + c;
        unsigned d0 = pkbf(W[0],      W[64]);
        unsigned d1 = pkbf(W[2 * 64], W[3 * 64]);
        unsigned d2 = pkbf(W[4 * 64], W[5 * 64]);
        unsigned d3 = pkbf(W[6 * 64], W[7 * 64]);
        int slot = ln ^ ((ln >> 3) & 7);
        SB[g][ks][tile][slot][0] = d0; SB[g][ks][tile][slot][1] = d1;
        SB[g][ks][tile][slot][2] = d2; SB[g][ks][tile][slot][3] = d3;
    }
    __syncthreads();
    int wv = t >> 6, lane = t & 63;
    int m = lane & 15, quad = lane >> 4;
    int slot = lane ^ ((lane >> 3) & 7);
    for (int tb = blockIdx.x * 4 + wv; tb < NTILES; tb += gridDim.x * 4) {
        int base = tb * 16;
        int pn = perm[base + m];
        gather_tile(cur, rowptr, csr, pn, m, quad, wv, XT);
        const u16* erow = ee  + (size_t)pn * 64;
        const u16* crow = cur + (size_t)pn * 64;
        int prw[4];
#pragma unroll
        for (int r = 0; r < 4; r++) prw[r] = perm[base + quad * 4 + r];
        f32x4 acc[4];
#pragma unroll
        for (int i = 0; i < 4; i++) acc[i] = (f32x4){0.f, 0.f, 0.f, 0.f};
        // GEMM1: k 0..63 = agg (XT), 64..127 = ee (global)
#pragma unroll
        for (int ks = 0; ks < 4; ks++) {
            bf16x8 a;
            if (ks < 2) {
                int gp = (ks * 4 + quad) ^ (m & 7);
                a = *(const bf16x8*)&XT[wv][m][gp * 8];
            } else {
                a = *(const bf16x8*)(erow + (ks - 2) * 32 + quad * 8);
            }
#pragma unroll
            for (int tile = 0; tile < 4; tile++) {
                bf16x8 b = *(const bf16x8*)&SB[0][ks][tile][slot][0];
                acc[tile] = __builtin_amdgcn_mfma_f32_16x16x32_bf16(a, b, acc[tile], 0, 0, 0);
            }
        }
        // relu(msg) -> XT (reuse) in A-readable swizzled layout (wave-private)
#pragma unroll
        for (int tile = 0; tile < 4; tile++)
#pragma unroll
            for (int r = 0; r < 4; r++) {
                int node = quad * 4 + r;
                int f = tile * 16 + m;
                int sidx = (((f >> 3) ^ (node & 7)) << 3) | (f & 7);
                XT[wv][node][sidx] = bf1(fmaxf(acc[tile][r], 0.f));
            }
        // GEMM2: k 0..63 = cur (global bf16), 64..127 = msg (XT)
#pragma unroll
        for (int i = 0; i < 4; i++) acc[i] = (f32x4){0.f, 0.f, 0.f, 0.f};
#pragma unroll
        for (int ks = 0; ks < 4; ks++) {
            bf16x8 a;
            if (ks < 2) {
                a = *(const bf16x8*)(crow + ks * 32 + quad * 8);
            } else {
                int gp = ((ks - 2) * 4 + quad) ^ (m & 7);
                a = *(const bf16x8*)&XT[wv][m][gp << 3];
            }
#pragma unroll
            for (int tile = 0; tile < 4; tile++) {
                bf16x8 b = *(const bf16x8*)&SB[1][ks][tile][slot][0];
                acc[tile] = __builtin_amdgcn_mfma_f32_16x16x32_bf16(a, b, acc[tile], 0, 0, 0);
            }
        }
#pragma unroll
        for (int tile = 0; tile < 4; tile++)
#pragma unroll
            for (int r = 0; r < 4; r++) {
                float v = fmaxf(acc[tile][r], 0.f);
                size_t oi = (size_t)prw[r] * 64 + tile * 16 + m;
                if (F32OUT) ((float*)outp)[oi] = v;
                else        ((u16*)outp)[oi] = (u16)bf1(v);
            }
    }
}

// R21: atomic-free means partials (distinct addresses, no done-counter).
__global__ __launch_bounds__(256) void k_means2(const float* __restrict__ cur,
                                                float* __restrict__ pmeans) {
    int g = blockIdx.x / MCHUNK;
    int c = blockIdx.x % MCHUNK;
    int t = threadIdx.x, f = t & 63, q = t >> 6;
    int base = g * NPG + c * MROWS;
    float acc = 0.f;
    for (int n = base + q; n < base + MROWS; n += 4) acc += cur[(size_t)n * 64 + f];
    __shared__ float red[4][64];
    red[q][f] = acc;
    __syncthreads();
    if (q == 0)
        pmeans[(size_t)(g * MCHUNK + c) * 64 + f] =
            red[0][f] + red[1][f] + red[2][f] + red[3][f];
}

// r1[g] = sum_f relu((mean[g] @ Wp)[f]) * Wr[f]. One block.
__global__ __launch_bounds__(256) void k_pool2(
        const float* __restrict__ pmeans, const float* __restrict__ Wp,
        const float* __restrict__ Wr, float* __restrict__ r1) {
    __shared__ float sm[4][64];
    int wv = threadIdx.x >> 6, lane = threadIdx.x & 63;
    for (int g = wv; g < NG; g += 4) {
        float m = 0.f;
        const float* pm = pmeans + (size_t)g * MCHUNK * 64 + lane;
#pragma unroll
        for (int c = 0; c < MCHUNK; c++) m += pm[c * 64];
        sm[wv][lane] = m * (1.0f / NPG);
        float a2 = 0.f;
#pragma unroll 16
        for (int k = 0; k < 64; k++) a2 = fmaf(sm[wv][k], Wp[k * 64 + lane], a2);
        float v = fmaxf(a2, 0.f) * Wr[lane];
        for (int off = 32; off; off >>= 1) v += __shfl_xor(v, off, 64);
        if (lane == 0) r1[g] = v;
    }
}

// out[n] = b + r1[batch[n]] + dot(relu(cur[n]), Wr[64:])
__global__ void k_read2(const float* __restrict__ cur, const float* __restrict__ r1,
                        const int* __restrict__ batch, const float* __restrict__ Wr,
                        const float* __restrict__ br, float* __restrict__ out) {
    int idx = blockIdx.x * 256 + threadIdx.x;
    int node = idx >> 4;
    if (node >= N_NODES) return;
    int q = idx & 15;
    float4 c = *(const float4*)(cur + (size_t)node * 64 + q * 4);
    float4 w = *(const float4*)(Wr + 64 + q * 4);
    float v = fmaxf(c.x, 0.f) * w.x + fmaxf(c.y, 0.f) * w.y
            + fmaxf(c.z, 0.f) * w.z + fmaxf(c.w, 0.f) * w.w;
    v += __shfl_xor(v, 1, 64); v += __shfl_xor(v, 2, 64);
    v += __shfl_xor(v, 4, 64); v += __shfl_xor(v, 8, 64);
    if (q == 0) out[node] = v + r1[batch[node]] + br[0];
}

// ---------------------------------------------------------------------------
extern "C" void kernel_launch(void* const* d_in, const int* in_sizes, int n_in,
                              void* d_out, int out_size, void* d_ws, size_t ws_size,
                              hipStream_t stream) {
    const float* x    = (const float*)d_in[0];
    const float* Wi   = (const float*)d_in[1];
    const float* We1  = (const float*)d_in[2];
    const float* We2  = (const float*)d_in[3];
    const float* Wm   = (const float*)d_in[4];   // [3,128,64]
    const float* Wu   = (const float*)d_in[5];   // [3,128,64]
    const float* Wp   = (const float*)d_in[6];
    const float* Wr   = (const float*)d_in[7];
    const float* br   = (const float*)d_in[8];
    const int*   ei   = (const int*)d_in[9];     // [2,E]
    const int*   batch= (const int*)d_in[10];
    const int* row = ei;
    const int* col = ei + N_EDGES;
    float* out = (float*)d_out;

    char* w = (char*)d_ws;
    size_t off = 0;
    auto carve = [&](size_t bytes) -> void* {
        void* p = (void*)(w + off);
        off += (bytes + 255) & ~(size_t)255;
        return p;
    };
    // zero-init region (one memset: dmax + hist + binBump + bktCnt)
    int*   dmax     = (int*)carve(256);
    int*   hist     = (int*)carve(256 * 4);
    int*   binBump  = (int*)carve(256 * 4);
    int*   bktCnt   = (int*)carve(256 * 4);
    size_t zero_span = off;
    unsigned* bktData = (unsigned*)carve((size_t)NBKT * BKT_CAP * 4);  // 4.8MB
    int*   deg      = (int*)carve((size_t)N_NODES * 4);   // dense, fully written
    int*   rowptr   = (int*)carve((size_t)(N_NODES + 1) * 4);
    u16*   csr      = (u16*)carve((size_t)N_EDGES * 2);
    int*   perm     = (int*)carve((size_t)N_NODES * 4);
    float* pmeans   = (float*)carve((size_t)NG * MCHUNK * 64 * 4);
    u16*   bufA     = (u16*)carve((size_t)N_NODES * 64 * 2);
    u16*   bufB     = (u16*)carve((size_t)N_NODES * 64 * 2);
    u16*   ee       = (u16*)carve((size_t)N_NODES * 64 * 2);
    float* curF     = (float*)carve((size_t)N_NODES * 64 * 4);
    float* r1       = (float*)carve((size_t)NG * 4);

    hipMemsetAsync(d_ws, 0, zero_span, stream);

    // R25 bucket-radix CSR build (atomic-light) fused with node init
    k_bucket_init<<<P1_BLKS + INIT_BLKS, 256, 0, stream>>>(row, col, bktCnt, bktData,
                                                           x, Wi, We1, bufA, bufB);
    // bsort: CSR + deg + rowptr + dmax + hist (unsorted lists, R28)
    k_bsort   <<<NBKT, 256, 0, stream>>>(bktData, bktCnt, deg, rowptr, csr,
                                         dmax, hist);
    // descending-degree counting-sort perm
    k_permsort<<<SCAN_NBLK, 256, 0, stream>>>(deg, hist, binBump, perm);

    // fused h-gather + edge embedding (bufB = h)
    k_edge_f<<<GATHER_BLKS, 256, 0, stream>>>(bufB, rowptr, csr, dmax, We2, perm, ee);

    // fused gather+layer x3: A->B, B->A, A->curF(fp32)
    k_flayer<false><<<GATHER_BLKS, 256, 0, stream>>>(bufA, ee, rowptr, csr,
                                                     Wm, Wu, perm, bufB);
    k_flayer<false><<<GATHER_BLKS, 256, 0, stream>>>(bufB, ee, rowptr, csr,
                                                     Wm + 128 * 64, Wu + 128 * 64,
                                                     perm, bufA);
    k_flayer<true> <<<GATHER_BLKS, 256, 0, stream>>>(bufA, ee, rowptr, csr,
                                                     Wm + 2 * 128 * 64, Wu + 2 * 128 * 64,
                                                     perm, curF);

    // atomic-free means partials -> tiny pool kernel
    k_means2<<<NG * MCHUNK, 256, 0, stream>>>(curF, pmeans);
    k_pool2 <<<1, 256, 0, stream>>>(pmeans, Wp, Wr, r1);
    k_read2<<<(N_NODES * 16 + 255) / 256, 256, 0, stream>>>(curF, r1, batch, Wr, br, out);
}